// Round 4
// baseline (1508.549 us; speedup 1.0000x reference)
//
#include <hip/hip_runtime.h>
#include <stdint.h>

#define E_NUM 1000000
#define NNODES 100000
#define NT 15625          // tiles of 64 edges
#define GRID_MAIN 512     // 2 blocks/CU x 256 CU, persistent grid-stride

typedef __attribute__((ext_vector_type(8))) short short8;
typedef __attribute__((ext_vector_type(4))) short short4v;
typedef __attribute__((ext_vector_type(4))) float f32x4;
typedef __attribute__((ext_vector_type(4))) unsigned int uint4v;

// ws layout (bytes)
static constexpr size_t OFF_ZU = 0;                       // 100000*128*2 = 25,600,000
static constexpr size_t OFF_ZB = 25600000;                // + 25,600,000
static constexpr size_t OFF_W1 = 51200000;                // 256*256*2 = 131072
static constexpr size_t OFF_W2 = 51200000 + 131072;
static constexpr size_t OFF_W3 = 51200000 + 262144;       // padded [16][256] bf16 = 8192

__device__ __forceinline__ uint16_t f2bf(float x) {
  union { float f; uint32_t u; } a; a.f = x;
  uint32_t r = a.u + 0x7fffu + ((a.u >> 16) & 1u);  // round-to-nearest-even
  return (uint16_t)(r >> 16);
}

__device__ __forceinline__ uint32_t pkbf(float a, float b) {
  uint32_t r;
  asm("v_cvt_pk_bf16_f32 %0, %1, %2" : "=v"(r) : "v"(a), "v"(b));
  return r;
}

__global__ void conv_z_kernel(const float* __restrict__ zu, const float* __restrict__ zb,
                              uint16_t* __restrict__ ou, uint16_t* __restrict__ ob) {
  const int64_t n4 = (int64_t)NNODES * 128 / 4;
  for (int64_t i = (int64_t)blockIdx.x * blockDim.x + threadIdx.x; i < n4;
       i += (int64_t)gridDim.x * blockDim.x) {
    float4 u = reinterpret_cast<const float4*>(zu)[i];
    float4 b = reinterpret_cast<const float4*>(zb)[i];
    short4v pu, pb;
    pu[0] = (short)f2bf(u.x); pu[1] = (short)f2bf(u.y);
    pu[2] = (short)f2bf(u.z); pu[3] = (short)f2bf(u.w);
    pb[0] = (short)f2bf(b.x); pb[1] = (short)f2bf(b.y);
    pb[2] = (short)f2bf(b.z); pb[3] = (short)f2bf(b.w);
    *reinterpret_cast<short4v*>(ou + i * 4) = pu;
    *reinterpret_cast<short4v*>(ob + i * 4) = pb;
  }
}

__global__ void conv_w_kernel(const float* __restrict__ W1, const float* __restrict__ W2,
                              const float* __restrict__ W3,
                              uint16_t* __restrict__ o1, uint16_t* __restrict__ o2,
                              uint16_t* __restrict__ o3) {
  const int i = blockIdx.x * 256 + threadIdx.x;
  if (i < 65536) {
    o1[i] = f2bf(W1[i]);
    o2[i] = f2bf(W2[i]);
  }
  if (i < 4096) {  // W3 padded [10][256] -> [16][256], zero rows
    const int r = i >> 8, c = i & 255;
    o3[i] = (r < 10) ? f2bf(W3[r * 256 + c]) : (uint16_t)0;
  }
}

// Persistent fused MLP. 512 threads = 8 waves = 4 hidden-quarters x 2 edge-halves.
// LDS: A = sm[0..32K) Z tile [64 edges][256 bf16] (XOR-swizzled, self-replacing dbuf);
//      B = sm[32K..64K) H1 [64][256 bf16], later overlaid by P partials (272B stride).
// Gather of tile t+1 issued right after GEMM1(t)'s barrier -> hidden under GEMM2/3.
// H2 stays in registers: cvt_pk -> shuffles build GEMM3 B-fragments.
__global__ __launch_bounds__(512, 4) void edge_mlp_kernel(
    const uint16_t* __restrict__ zu, const uint16_t* __restrict__ zb,
    const int* __restrict__ eidx,
    const uint16_t* __restrict__ w1, const uint16_t* __restrict__ w2,
    const uint16_t* __restrict__ w3,
    const float* __restrict__ b1, const float* __restrict__ b2,
    const float* __restrict__ b3v,
    float* __restrict__ out)
{
  __shared__ __align__(16) unsigned char sm[65536];

  const int tid = (int)threadIdx.x;
  const int w  = tid >> 6;
  const int l  = tid & 63;
  const int lg = l >> 4;    // 0..3
  const int lc = l & 15;    // 0..15
  const int hq = w >> 1;    // hidden quarter (64 rows)
  const int eh = w & 1;     // edge half (32 edges)
  const int g_half = (l >> 4) & 1;  // gather: 0=user 1=book
  const int g_row  = l >> 5;        // gather: row within pair

  // ds_read bases: addr(m,k0) = e*512 + ((k0*64+lg*16) ^ ((e&7)<<4))
  //   = baseE[m] (^64 if k0 odd) + (k0>>1)*128   [+32768 for H1]
  int baseE[2], baseO[2];
  #pragma unroll
  for (int m = 0; m < 2; ++m) {
    baseE[m] = ((2*eh + m)*16 + lc) * 512 + ((lg ^ (lc & 3)) << 4) + (((lc >> 2) & 1) << 6);
    baseO[m] = baseE[m] ^ 64;
  }

  const int stride = (int)gridDim.x;
  int t = (int)blockIdx.x;
  int pf[4];

  // ---- prologue: idx(t), gather(t), idx(t+stride) ----
  {
    const int tc = t < NT ? t : NT - 1;
    #pragma unroll
    for (int i = 0; i < 4; ++i) {
      const int eg = tc*64 + w*8 + i*2 + g_row;
      pf[i] = eidx[g_half ? (E_NUM + eg) : eg];
    }
  }
  if (t < NT) {
    #pragma unroll
    for (int i = 0; i < 4; ++i) {
      int ni = pf[i]; ni = ni < 0 ? 0 : (ni >= NNODES ? NNODES - 1 : ni);
      const int eloc = w*8 + i*2 + g_row;
      const int cch = (l & 8) | ((l & 7) ^ (eloc & 7));   // pre-swizzled source chunk
      const uint16_t* gp = (g_half ? zb : zu) + (size_t)ni*128 + cch*8;
      __builtin_amdgcn_global_load_lds((const __attribute__((address_space(1))) void*)gp,
          (__attribute__((address_space(3))) void*)(sm + (w*8 + i*2)*512), 16, 0, 0);
    }
  }
  {
    const int tn = t + stride; const int tc = tn < NT ? tn : NT - 1;
    #pragma unroll
    for (int i = 0; i < 4; ++i) {
      const int eg = tc*64 + w*8 + i*2 + g_row;
      pf[i] = eidx[g_half ? (E_NUM + eg) : eg];
    }
  }
  asm volatile("s_waitcnt vmcnt(0)" ::: "memory");
  __syncthreads();

  for (; t < NT; t += stride) {
    // ---------------- GEMM1: H1^T = W1 * Z^T ----------------
    f32x4 acc[4][2];
    #pragma unroll
    for (int ht = 0; ht < 4; ++ht)
      #pragma unroll
      for (int m = 0; m < 2; ++m) acc[ht][m] = (f32x4){0.f,0.f,0.f,0.f};
    #pragma unroll
    for (int k0 = 0; k0 < 8; ++k0) {
      short8 af[4];
      #pragma unroll
      for (int ht = 0; ht < 4; ++ht)
        af[ht] = *reinterpret_cast<const short8*>(w1 + (size_t)(hq*64 + ht*16 + lc)*256 + k0*32 + lg*8);
      short8 bf[2];
      #pragma unroll
      for (int m = 0; m < 2; ++m)
        bf[m] = *reinterpret_cast<const short8*>(sm + ((k0 & 1) ? baseO[m] : baseE[m]) + (k0 >> 1)*128);
      #pragma unroll
      for (int ht = 0; ht < 4; ++ht)
        #pragma unroll
        for (int m = 0; m < 2; ++m)
          acc[ht][m] = __builtin_amdgcn_mfma_f32_16x16x32_bf16(af[ht], bf[m], acc[ht][m], 0, 0, 0);
    }
    // ---------------- epilogue1: bias+relu+pack -> H1 (B region) ----------------
    #pragma unroll
    for (int ht = 0; ht < 4; ++ht) {
      const float4 bb = *reinterpret_cast<const float4*>(b1 + hq*64 + ht*16 + lg*4);
      const int colw = (128*hq + 32*ht + 8*lg) ^ ((lc & 7) << 4);
      #pragma unroll
      for (int m = 0; m < 2; ++m) {
        const int e = (2*eh + m)*16 + lc;
        const uint32_t lo = pkbf(fmaxf(acc[ht][m][0] + bb.x, 0.f), fmaxf(acc[ht][m][1] + bb.y, 0.f));
        const uint32_t hi = pkbf(fmaxf(acc[ht][m][2] + bb.z, 0.f), fmaxf(acc[ht][m][3] + bb.w, 0.f));
        *reinterpret_cast<uint2*>(sm + 32768 + e*512 + colw) = make_uint2(lo, hi);
      }
    }
    __syncthreads();   // A dead, H1 ready

    // ---------------- issue gather(t+stride) into A; prefetch idx(t+2*stride) ----------------
    if (t + stride < NT) {
      #pragma unroll
      for (int i = 0; i < 4; ++i) {
        int ni = pf[i]; ni = ni < 0 ? 0 : (ni >= NNODES ? NNODES - 1 : ni);
        const int eloc = w*8 + i*2 + g_row;
        const int cch = (l & 8) | ((l & 7) ^ (eloc & 7));
        const uint16_t* gp = (g_half ? zb : zu) + (size_t)ni*128 + cch*8;
        __builtin_amdgcn_global_load_lds((const __attribute__((address_space(1))) void*)gp,
            (__attribute__((address_space(3))) void*)(sm + (w*8 + i*2)*512), 16, 0, 0);
      }
    }
    {
      const int tn = t + 2*stride; const int tc = tn < NT ? tn : NT - 1;
      #pragma unroll
      for (int i = 0; i < 4; ++i) {
        const int eg = tc*64 + w*8 + i*2 + g_row;
        pf[i] = eidx[g_half ? (E_NUM + eg) : eg];
      }
    }

    // ---------------- GEMM2: H2^T = W2 * H1^T ----------------
    f32x4 acc2[4][2];
    #pragma unroll
    for (int ht = 0; ht < 4; ++ht)
      #pragma unroll
      for (int m = 0; m < 2; ++m) acc2[ht][m] = (f32x4){0.f,0.f,0.f,0.f};
    #pragma unroll
    for (int k0 = 0; k0 < 8; ++k0) {
      short8 af[4];
      #pragma unroll
      for (int ht = 0; ht < 4; ++ht)
        af[ht] = *reinterpret_cast<const short8*>(w2 + (size_t)(hq*64 + ht*16 + lc)*256 + k0*32 + lg*8);
      short8 bf[2];
      #pragma unroll
      for (int m = 0; m < 2; ++m)
        bf[m] = *reinterpret_cast<const short8*>(sm + 32768 + ((k0 & 1) ? baseO[m] : baseE[m]) + (k0 >> 1)*128);
      #pragma unroll
      for (int ht = 0; ht < 4; ++ht)
        #pragma unroll
        for (int m = 0; m < 2; ++m)
          acc2[ht][m] = __builtin_amdgcn_mfma_f32_16x16x32_bf16(af[ht], bf[m], acc2[ht][m], 0, 0, 0);
    }

    // ---------------- epilogue2: bias+relu+pack H2 (registers only) ----------------
    uint32_t pk2[4][2][2];
    #pragma unroll
    for (int ht = 0; ht < 4; ++ht) {
      const float4 bb = *reinterpret_cast<const float4*>(b2 + hq*64 + ht*16 + lg*4);
      #pragma unroll
      for (int m = 0; m < 2; ++m) {
        pk2[ht][m][0] = pkbf(fmaxf(acc2[ht][m][0] + bb.x, 0.f), fmaxf(acc2[ht][m][1] + bb.y, 0.f));
        pk2[ht][m][1] = pkbf(fmaxf(acc2[ht][m][2] + bb.z, 0.f), fmaxf(acc2[ht][m][3] + bb.w, 0.f));
      }
    }

    // ---------------- GEMM3: shuffle H2 frags, partial over wave's 64 h2 ----------------
    f32x4 acc3[2];
    acc3[0] = (f32x4){0.f,0.f,0.f,0.f};
    acc3[1] = (f32x4){0.f,0.f,0.f,0.f};
    const int ls = lc + ((lg & 1) << 5);
    const bool hiht = (lg >= 2);
    #pragma unroll
    for (int kap = 0; kap < 2; ++kap) {
      const short8 a3 = *reinterpret_cast<const short8*>(w3 + (size_t)lc*256 + hq*64 + kap*32 + lg*8);
      #pragma unroll
      for (int m = 0; m < 2; ++m) {
        const uint32_t x0a = (uint32_t)__shfl((int)pk2[2*kap+0][m][0], ls);
        const uint32_t x0b = (uint32_t)__shfl((int)pk2[2*kap+1][m][0], ls);
        const uint32_t x1a = (uint32_t)__shfl((int)pk2[2*kap+0][m][1], ls);
        const uint32_t x1b = (uint32_t)__shfl((int)pk2[2*kap+1][m][1], ls);
        const uint32_t x2a = (uint32_t)__shfl((int)pk2[2*kap+0][m][0], ls + 16);
        const uint32_t x2b = (uint32_t)__shfl((int)pk2[2*kap+1][m][0], ls + 16);
        const uint32_t x3a = (uint32_t)__shfl((int)pk2[2*kap+0][m][1], ls + 16);
        const uint32_t x3b = (uint32_t)__shfl((int)pk2[2*kap+1][m][1], ls + 16);
        union { uint4v u; short8 s; } cv;
        cv.u = (uint4v){ hiht ? x0b : x0a, hiht ? x1b : x1a,
                         hiht ? x2b : x2a, hiht ? x3b : x3a };
        acc3[m] = __builtin_amdgcn_mfma_f32_16x16x32_bf16(a3, cv.s, acc3[m], 0, 0, 0);
      }
    }
    __syncthreads();   // all H1 reads done -> B reusable for partials

    // ---------------- partials P[e][hq][n16] (272B row stride) ----------------
    #pragma unroll
    for (int m = 0; m < 2; ++m) {
      const int e = (2*eh + m)*16 + lc;
      *reinterpret_cast<f32x4*>(sm + 32768 + e*272 + hq*64 + lg*16) = acc3[m];
    }
    __syncthreads();

    // ---------------- reduce(4) + log_softmax + store ----------------
    {
      const int e = tid >> 3, s = tid & 7;
      float v0 = 0.f, v1 = 0.f;
      #pragma unroll
      for (int q = 0; q < 4; ++q) {
        const float2 pv = *reinterpret_cast<const float2*>(sm + 32768 + e*272 + q*64 + s*8);
        v0 += pv.x; v1 += pv.y;
      }
      if (s < 5) { v0 += b3v[2*s]; v1 += b3v[2*s + 1]; }
      else       { v0 = -1e30f;   v1 = -1e30f; }
      float mx = fmaxf(v0, v1);
      mx = fmaxf(mx, __shfl_xor(mx, 1));
      mx = fmaxf(mx, __shfl_xor(mx, 2));
      mx = fmaxf(mx, __shfl_xor(mx, 4));
      float se = (s < 5) ? (__expf(v0 - mx) + __expf(v1 - mx)) : 0.f;
      se += __shfl_xor(se, 1);
      se += __shfl_xor(se, 2);
      se += __shfl_xor(se, 4);
      const float lse = mx + __logf(se);
      if (s < 5) {
        float* po = out + ((size_t)t*64 + e)*10 + 2*s;
        *reinterpret_cast<float2*>(po) = make_float2(v0 - lse, v1 - lse);
      }
    }
    asm volatile("s_waitcnt vmcnt(0)" ::: "memory");  // gather(t+stride) landed
    __syncthreads();
  }
}

extern "C" void kernel_launch(void* const* d_in, const int* in_sizes, int n_in,
                              void* d_out, int out_size, void* d_ws, size_t ws_size,
                              hipStream_t stream) {
  const float* z_user = (const float*)d_in[0];
  const float* z_book = (const float*)d_in[1];
  const int*   eidx   = (const int*)d_in[2];
  const float* W1     = (const float*)d_in[3];
  const float* b1     = (const float*)d_in[4];
  const float* W2     = (const float*)d_in[5];
  const float* b2     = (const float*)d_in[6];
  const float* W3     = (const float*)d_in[7];
  const float* b3     = (const float*)d_in[8];
  float* out = (float*)d_out;

  uint8_t* ws = (uint8_t*)d_ws;
  uint16_t* zu_b = (uint16_t*)(ws + OFF_ZU);
  uint16_t* zb_b = (uint16_t*)(ws + OFF_ZB);
  uint16_t* w1_b = (uint16_t*)(ws + OFF_W1);
  uint16_t* w2_b = (uint16_t*)(ws + OFF_W2);
  uint16_t* w3_b = (uint16_t*)(ws + OFF_W3);

  conv_z_kernel<<<2048, 256, 0, stream>>>(z_user, z_book, zu_b, zb_b);
  conv_w_kernel<<<256, 256, 0, stream>>>(W1, W2, W3, w1_b, w2_b, w3_b);
  edge_mlp_kernel<<<GRID_MAIN, 512, 0, stream>>>(zu_b, zb_b, eidx,
                                                 w1_b, w2_b, w3_b,
                                                 b1, b2, b3, out);
}

// Round 8
// 533.969 us; speedup vs baseline: 2.8252x; 2.8252x over previous
//
#include <hip/hip_runtime.h>
#include <stdint.h>

#define E_NUM 1000000
#define NNODES 100000
#define M_TILE 128
#define NBLK 7813   // ceil(1e6 / 128)

typedef __attribute__((ext_vector_type(8))) short short8;
typedef __attribute__((ext_vector_type(4))) short short4v;
typedef __attribute__((ext_vector_type(4))) float f32x4;

// ws layout (bytes)
static constexpr size_t OFF_ZU = 0;                       // 100000*128*2 = 25,600,000
static constexpr size_t OFF_ZB = 25600000;                // + 25,600,000
static constexpr size_t OFF_W1 = 51200000;                // 256*256*2 = 131072
static constexpr size_t OFF_W2 = 51200000 + 131072;
static constexpr size_t OFF_W3 = 51200000 + 262144;       // padded [16][256] bf16 = 8192

__device__ __forceinline__ uint16_t f2bf(float x) {
  union { float f; uint32_t u; } a; a.f = x;
  uint32_t r = a.u + 0x7fffu + ((a.u >> 16) & 1u);  // round-to-nearest-even
  return (uint16_t)(r >> 16);
}

__device__ __forceinline__ uint32_t pkbf(float a, float b) {
  uint32_t r;
  asm("v_cvt_pk_bf16_f32 %0, %1, %2" : "=v"(r) : "v"(a), "v"(b));
  return r;
}

__global__ void conv_z_kernel(const float* __restrict__ zu, const float* __restrict__ zb,
                              uint16_t* __restrict__ ou, uint16_t* __restrict__ ob) {
  const int64_t n4 = (int64_t)NNODES * 128 / 4;
  for (int64_t i = (int64_t)blockIdx.x * blockDim.x + threadIdx.x; i < n4;
       i += (int64_t)gridDim.x * blockDim.x) {
    float4 u = reinterpret_cast<const float4*>(zu)[i];
    float4 b = reinterpret_cast<const float4*>(zb)[i];
    short4v pu, pb;
    pu[0] = (short)f2bf(u.x); pu[1] = (short)f2bf(u.y);
    pu[2] = (short)f2bf(u.z); pu[3] = (short)f2bf(u.w);
    pb[0] = (short)f2bf(b.x); pb[1] = (short)f2bf(b.y);
    pb[2] = (short)f2bf(b.z); pb[3] = (short)f2bf(b.w);
    *reinterpret_cast<short4v*>(ou + i * 4) = pu;
    *reinterpret_cast<short4v*>(ob + i * 4) = pb;
  }
}

__global__ void conv_w_kernel(const float* __restrict__ W1, const float* __restrict__ W2,
                              const float* __restrict__ W3,
                              uint16_t* __restrict__ o1, uint16_t* __restrict__ o2,
                              uint16_t* __restrict__ o3) {
  const int i = blockIdx.x * 256 + threadIdx.x;
  if (i < 65536) {
    o1[i] = f2bf(W1[i]);
    o2[i] = f2bf(W2[i]);
  }
  if (i < 4096) {  // W3 padded [10][256] -> [16][256], zero rows
    const int r = i >> 8, c = i & 255;
    o3[i] = (r < 10) ? f2bf(W3[r * 256 + c]) : (uint16_t)0;
  }
}

// Fused MLP, NON-persistent (phase-synchronized blocks keep weights L2-hot; the
// R2 persistent grid thrashed L2 -> FETCH 2.7GB). M=128 edges/block, 8 waves.
// Each wave owns a DISJOINT 32-row hidden slice -> each W element read once per
// block per GEMM (1 KB/edge of weight requests, half of R1's rate).
// Single 64 KB LDS buffer reused in place: Z tile -> H1 -> H2 (accumulators stay
// in AGPRs across each GEMM; write-back happens after a barrier). 2 blocks/CU.
__global__ __launch_bounds__(512, 4) void edge_mlp_kernel(
    const uint16_t* __restrict__ zu, const uint16_t* __restrict__ zb,
    const int* __restrict__ eidx,
    const uint16_t* __restrict__ w1, const uint16_t* __restrict__ w2,
    const uint16_t* __restrict__ w3,
    const float* __restrict__ b1, const float* __restrict__ b2,
    const float* __restrict__ b3v,
    float* __restrict__ out)
{
  __shared__ __align__(16) unsigned char buf[65536];   // [128 edges][512 B], XOR-swizzled

  const int tid = (int)threadIdx.x;
  const int w  = tid >> 6;          // 0..7
  const int l  = tid & 63;
  const int lg = l >> 4;            // 0..3
  const int lc = l & 15;            // 0..15
  const int g_half = (l >> 4) & 1;  // gather: 0=user 1=book
  const int g_row  = l >> 5;        // gather: edge within pair
  const int e0 = (int)blockIdx.x * M_TILE;

  // ---- gather: 128 edges, [user 256B | book 256B] per 512-B row, swizzled source ----
  #pragma unroll
  for (int i = 0; i < 8; ++i) {
    const int eloc = w*16 + i*2 + g_row;
    int eg = e0 + eloc; if (eg >= E_NUM) eg = E_NUM - 1;
    int ni = eidx[g_half ? (E_NUM + eg) : eg];
    ni = ni < 0 ? 0 : (ni >= NNODES ? NNODES - 1 : ni);
    const int cc = lc ^ (eloc & 7);                    // pre-swizzled source chunk
    const uint16_t* gp = (g_half ? zb : zu) + (size_t)ni*128 + cc*8;
    __builtin_amdgcn_global_load_lds((const __attribute__((address_space(1))) void*)gp,
        (__attribute__((address_space(3))) void*)(buf + (w*16 + i*2)*512), 16, 0, 0);
  }
  __syncthreads();   // drains vmcnt

  // B-fragment address: elem k of edge e at byte e*512 + ((k*2) ^ ((e&7)<<4));
  // e&7 == lc&7 for all our reads. Decompose: bbase + ((k0 ^ lc4)<<6), k0 = k/32.
  const int bbase = lc*512 + ((lg ^ (lc & 3)) << 4);
  const int lc4  = (lc >> 2) & 1;
  const int rb   = w*32 + lc;       // wave's hidden slice rows (ht*16 offset added)

  f32x4 acc[2][8];

  // ================= GEMM1: H1^T = W1 * Z^T =================
  #pragma unroll
  for (int ht = 0; ht < 2; ++ht)
    #pragma unroll
    for (int ms = 0; ms < 8; ++ms) acc[ht][ms] = (f32x4){0.f,0.f,0.f,0.f};
  #pragma unroll
  for (int k0 = 0; k0 < 8; ++k0) {
    const short8 a0 = *reinterpret_cast<const short8*>(w1 + (size_t)rb*256        + k0*32 + lg*8);
    const short8 a1 = *reinterpret_cast<const short8*>(w1 + (size_t)(rb + 16)*256 + k0*32 + lg*8);
    const int ko = ((k0 ^ lc4) << 6);
    #pragma unroll
    for (int ms = 0; ms < 8; ++ms) {
      const short8 bf = *reinterpret_cast<const short8*>(buf + ms*8192 + bbase + ko);
      acc[0][ms] = __builtin_amdgcn_mfma_f32_16x16x32_bf16(a0, bf, acc[0][ms], 0, 0, 0);
      acc[1][ms] = __builtin_amdgcn_mfma_f32_16x16x32_bf16(a1, bf, acc[1][ms], 0, 0, 0);
    }
  }
  __syncthreads();   // everyone done reading Z
  #pragma unroll
  for (int ht = 0; ht < 2; ++ht) {
    const float4 bb = *reinterpret_cast<const float4*>(b1 + w*32 + ht*16 + lg*4);
    const int colw = (w*64 + ht*32 + lg*8) ^ ((lc & 7) << 4);
    #pragma unroll
    for (int ms = 0; ms < 8; ++ms) {
      uint2 pk;
      pk.x = pkbf(fmaxf(acc[ht][ms][0] + bb.x, 0.f), fmaxf(acc[ht][ms][1] + bb.y, 0.f));
      pk.y = pkbf(fmaxf(acc[ht][ms][2] + bb.z, 0.f), fmaxf(acc[ht][ms][3] + bb.w, 0.f));
      *reinterpret_cast<uint2*>(buf + (ms*16 + lc)*512 + colw) = pk;
    }
  }
  __syncthreads();   // H1 ready

  // ================= GEMM2: H2^T = W2 * H1^T =================
  #pragma unroll
  for (int ht = 0; ht < 2; ++ht)
    #pragma unroll
    for (int ms = 0; ms < 8; ++ms) acc[ht][ms] = (f32x4){0.f,0.f,0.f,0.f};
  #pragma unroll
  for (int k0 = 0; k0 < 8; ++k0) {
    const short8 a0 = *reinterpret_cast<const short8*>(w2 + (size_t)rb*256        + k0*32 + lg*8);
    const short8 a1 = *reinterpret_cast<const short8*>(w2 + (size_t)(rb + 16)*256 + k0*32 + lg*8);
    const int ko = ((k0 ^ lc4) << 6);
    #pragma unroll
    for (int ms = 0; ms < 8; ++ms) {
      const short8 bf = *reinterpret_cast<const short8*>(buf + ms*8192 + bbase + ko);
      acc[0][ms] = __builtin_amdgcn_mfma_f32_16x16x32_bf16(a0, bf, acc[0][ms], 0, 0, 0);
      acc[1][ms] = __builtin_amdgcn_mfma_f32_16x16x32_bf16(a1, bf, acc[1][ms], 0, 0, 0);
    }
  }
  __syncthreads();   // everyone done reading H1
  #pragma unroll
  for (int ht = 0; ht < 2; ++ht) {
    const float4 bb = *reinterpret_cast<const float4*>(b2 + w*32 + ht*16 + lg*4);
    const int colw = (w*64 + ht*32 + lg*8) ^ ((lc & 7) << 4);
    #pragma unroll
    for (int ms = 0; ms < 8; ++ms) {
      uint2 pk;
      pk.x = pkbf(fmaxf(acc[ht][ms][0] + bb.x, 0.f), fmaxf(acc[ht][ms][1] + bb.y, 0.f));
      pk.y = pkbf(fmaxf(acc[ht][ms][2] + bb.z, 0.f), fmaxf(acc[ht][ms][3] + bb.w, 0.f));
      *reinterpret_cast<uint2*>(buf + (ms*16 + lc)*512 + colw) = pk;
    }
  }
  __syncthreads();   // H2 ready

  // ================= GEMM3: O^T = W3pad * H2^T ; wave w owns edges [w*16, w*16+16) =================
  f32x4 acc3 = (f32x4){0.f,0.f,0.f,0.f};
  const int e3base = (w*16 + lc)*512 + ((lg ^ (lc & 3)) << 4);
  #pragma unroll
  for (int k0 = 0; k0 < 8; ++k0) {
    const short8 a3  = *reinterpret_cast<const short8*>(w3 + (size_t)lc*256 + k0*32 + lg*8);
    const short8 b3f = *reinterpret_cast<const short8*>(buf + e3base + ((k0 ^ lc4) << 6));
    acc3 = __builtin_amdgcn_mfma_f32_16x16x32_bf16(a3, b3f, acc3, 0, 0, 0);
  }

  // ---- log_softmax over n=0..9 ; lane holds n = lg*4 + r for its edge ----
  float vv[4];
  float mx = -3.0e38f;
  #pragma unroll
  for (int r = 0; r < 4; ++r) {
    const int n = lg*4 + r;
    const float x = acc3[r] + ((n < 10) ? b3v[n] : 0.f);
    vv[r] = x;
    if (n < 10) mx = fmaxf(mx, x);
  }
  mx = fmaxf(mx, __shfl_xor(mx, 16));
  mx = fmaxf(mx, __shfl_xor(mx, 32));
  float s = 0.f;
  #pragma unroll
  for (int r = 0; r < 4; ++r) {
    const int n = lg*4 + r;
    if (n < 10) s += __expf(vv[r] - mx);
  }
  s += __shfl_xor(s, 16);
  s += __shfl_xor(s, 32);
  const float lse = mx + __logf(s);

  const int e = e0 + w*16 + lc;
  if (e < E_NUM) {
    float* po = out + (size_t)e*10;
    if (lg == 0) {
      *reinterpret_cast<float2*>(po)     = make_float2(vv[0] - lse, vv[1] - lse);
      *reinterpret_cast<float2*>(po + 2) = make_float2(vv[2] - lse, vv[3] - lse);
    } else if (lg == 1) {
      *reinterpret_cast<float2*>(po + 4) = make_float2(vv[0] - lse, vv[1] - lse);
      *reinterpret_cast<float2*>(po + 6) = make_float2(vv[2] - lse, vv[3] - lse);
    } else if (lg == 2) {
      *reinterpret_cast<float2*>(po + 8) = make_float2(vv[0] - lse, vv[1] - lse);
    }
  }
}

extern "C" void kernel_launch(void* const* d_in, const int* in_sizes, int n_in,
                              void* d_out, int out_size, void* d_ws, size_t ws_size,
                              hipStream_t stream) {
  const float* z_user = (const float*)d_in[0];
  const float* z_book = (const float*)d_in[1];
  const int*   eidx   = (const int*)d_in[2];
  const float* W1     = (const float*)d_in[3];
  const float* b1     = (const float*)d_in[4];
  const float* W2     = (const float*)d_in[5];
  const float* b2     = (const float*)d_in[6];
  const float* W3     = (const float*)d_in[7];
  const float* b3     = (const float*)d_in[8];
  float* out = (float*)d_out;

  uint8_t* ws = (uint8_t*)d_ws;
  uint16_t* zu_b = (uint16_t*)(ws + OFF_ZU);
  uint16_t* zb_b = (uint16_t*)(ws + OFF_ZB);
  uint16_t* w1_b = (uint16_t*)(ws + OFF_W1);
  uint16_t* w2_b = (uint16_t*)(ws + OFF_W2);
  uint16_t* w3_b = (uint16_t*)(ws + OFF_W3);

  conv_z_kernel<<<2048, 256, 0, stream>>>(z_user, z_book, zu_b, zb_b);
  conv_w_kernel<<<256, 256, 0, stream>>>(W1, W2, W3, w1_b, w2_b, w3_b);
  edge_mlp_kernel<<<NBLK, 512, 0, stream>>>(zu_b, zb_b, eidx,
                                            w1_b, w2_b, w3_b,
                                            b1, b2, b3, out);
}